// Round 12
// baseline (225.297 us; speedup 1.0000x reference)
//
#include <hip/hip_runtime.h>
#include <hip/hip_fp16.h>

// BilinearMixture. Factorial record: bytes(R5), L2-locality(R6), instr
// count(R9), MLP(R9), lookup count(R11) each varied ~2x -> time pinned
// 101-125us. Best = R9 (101us). R12 = exact R9 structure + ONE probe:
// __builtin_nontemporal_load on feature-row gathers (nt -> no L1 allocate).
// Random gathers have ~0% L1 hit rate, so L1 allocation is pure overhead
// (evictions + tag/fill + longer MSHR occupancy). If the wall includes the
// L1 path, this frees it; if null, the gather-latency roofline is declared.

typedef _Float16 f16x8 __attribute__((ext_vector_type(8)));
typedef _Float16 h2    __attribute__((ext_vector_type(2)));

union F16x8 { f16x8 v; h2 h[4]; };

template <int CTRL>
__device__ __forceinline__ float dpp_add(float x) {
    int t = __builtin_amdgcn_update_dpp(0, __float_as_int(x), CTRL, 0xF, 0xF, true);
    return x + __int_as_float(t);
}
// Sum (a,b,c) across each 8-lane group: xor1 (quad_perm 0xB1), xor2 (0x4E),
// then ROW_HALF_MIRROR (0x141) folds the two quads of each half-row.
__device__ __forceinline__ void reduce8_3(float& a, float& b, float& c) {
    a = dpp_add<0xB1>(a);  b = dpp_add<0xB1>(b);  c = dpp_add<0xB1>(c);
    a = dpp_add<0x4E>(a);  b = dpp_add<0x4E>(b);  c = dpp_add<0x4E>(c);
    a = dpp_add<0x141>(a); b = dpp_add<0x141>(b); c = dpp_add<0x141>(c);
}

__device__ __forceinline__ float dot2acc(h2 a, h2 b, float c) {
#if __has_builtin(__builtin_amdgcn_fdot2)
    return __builtin_amdgcn_fdot2(a, b, c, false);
#else
    return c + (float)a[0] * (float)b[0] + (float)a[1] * (float)b[1];
#endif
}

// ---------- conversion: fp32 tables -> fp16 in workspace (proven ~free) ----
__global__ __launch_bounds__(256) void convert_tables_fp16(
    const float* __restrict__ u_feat, const float* __restrict__ v_feat,
    __half* __restrict__ u_h, __half* __restrict__ v_h, int nu, int nv)
{
    const int tid  = blockIdx.x * blockDim.x + threadIdx.x;
    const int nthr = gridDim.x * blockDim.x;
    for (int i = tid * 4; i < nu; i += nthr * 4) {
        const float4 x = *reinterpret_cast<const float4*>(u_feat + i);
        *reinterpret_cast<__half2*>(u_h + i)     = __floats2half2_rn(x.x, x.y);
        *reinterpret_cast<__half2*>(u_h + i + 2) = __floats2half2_rn(x.z, x.w);
    }
    for (int i = tid * 4; i < nv; i += nthr * 4) {
        const float4 x = *reinterpret_cast<const float4*>(v_feat + i);
        *reinterpret_cast<__half2*>(v_h + i)     = __floats2half2_rn(x.x, x.y);
        *reinterpret_cast<__half2*>(v_h + i + 2) = __floats2half2_rn(x.z, x.w);
    }
}

// ---------- main: 8 lanes/edge, 2 rounds (16 edges) per wave-iteration -----
__global__ __launch_bounds__(256) void bilinear_dot8(
    const __half* __restrict__ u_h, const __half* __restrict__ v_h,
    const float* __restrict__ W, const float* __restrict__ scalars,
    const float* __restrict__ u_bias, const float* __restrict__ v_bias,
    const int* __restrict__ u_idx, const int* __restrict__ v_idx,
    float* __restrict__ out, int E)
{
    const int lane = threadIdx.x & 63;
    const int sl   = lane & 7;                      // lane in 8-group
    const int sg   = lane >> 3;                     // subgroup (edge slot) 0..7
    const int wid  = (blockIdx.x * blockDim.x + threadIdx.x) >> 6;
    const int nw   = (gridDim.x * blockDim.x) >> 6;

    // Lane's W slice, packed fp16: wk[k][j2] covers d = sl*8 + 2*j2 (+1).
    const int d0 = sl * 8;
    h2 wk[3][4];
    #pragma unroll
    for (int k = 0; k < 3; ++k)
        #pragma unroll
        for (int j = 0; j < 4; ++j) {
            wk[k][j][0] = (_Float16)W[k * 64 + d0 + 2 * j];
            wk[k][j][1] = (_Float16)W[k * 64 + d0 + 2 * j + 1];
        }
    float s0 = 0.f, s1 = 0.f, s2 = 0.f;
    if (sl < 5) { s0 = scalars[sl]; s1 = scalars[5 + sl]; s2 = scalars[10 + sl]; }

    const int step = nw * 16;
    int base = wid * 16;
    if (base >= E) return;

    // Prologue indices for both rounds; loop prefetches the next iteration's.
    int ea = base + sg, eb = base + 8 + sg;
    int ua = u_idx[min(ea, E - 1)], va = v_idx[min(ea, E - 1)];
    int ub = u_idx[min(eb, E - 1)], vb = v_idx[min(eb, E - 1)];

    for (; base < E; base += step) {
        const int cea = base + sg, ceb = base + 8 + sg;
        const int cua = ua, cva = va, cub = ub, cvb = vb;

        // Row gathers: 16B/lane, nontemporal (no L1 allocate — zero-reuse
        // random stream; frees L1 tag/fill path and shortens MSHR occupancy).
        F16x8 Ua, Va, Ub, Vb;
        Ua.v = __builtin_nontemporal_load(
            reinterpret_cast<const f16x8*>(u_h + (size_t)cua * 64 + d0));
        Va.v = __builtin_nontemporal_load(
            reinterpret_cast<const f16x8*>(v_h + (size_t)cva * 64 + d0));
        Ub.v = __builtin_nontemporal_load(
            reinterpret_cast<const f16x8*>(u_h + (size_t)cub * 64 + d0));
        Vb.v = __builtin_nontemporal_load(
            reinterpret_cast<const f16x8*>(v_h + (size_t)cvb * 64 + d0));

        // Prefetch next iteration's indices (breaks idx->gather chain).
        const int nb = base + step;
        if (nb < E) {
            const int nea = nb + sg, neb = nb + 8 + sg;
            ua = u_idx[min(nea, E - 1)]; va = v_idx[min(nea, E - 1)];
            ub = u_idx[min(neb, E - 1)]; vb = v_idx[min(neb, E - 1)];
        }

        // Bias gathers early (writer lanes only); small L2-resident tables,
        // keep cacheable. Hide under dot/reduce.
        float bua = 0.f, bva = 0.f, bub = 0.f, bvb = 0.f;
        if (sl < 5) {
            bua = u_bias[(size_t)cua * 5 + sl];
            bva = v_bias[(size_t)cva * 5 + sl];
            bub = u_bias[(size_t)cub * 5 + sl];
            bvb = v_bias[(size_t)cvb * 5 + sl];
        }

        // Products in fp16 (v_pk_mul_f16 x4 per round).
        F16x8 Pa, Pb;
        Pa.v = Ua.v * Va.v;
        Pb.v = Ub.v * Vb.v;

        // K=3 partials via dot2 chains (f32 accumulate, no cvt storm).
        float qa0 = 0.f, qa1 = 0.f, qa2 = 0.f;
        float qb0 = 0.f, qb1 = 0.f, qb2 = 0.f;
        #pragma unroll
        for (int j = 0; j < 4; ++j) {
            qa0 = dot2acc(Pa.h[j], wk[0][j], qa0);
            qa1 = dot2acc(Pa.h[j], wk[1][j], qa1);
            qa2 = dot2acc(Pa.h[j], wk[2][j], qa2);
            qb0 = dot2acc(Pb.h[j], wk[0][j], qb0);
            qb1 = dot2acc(Pb.h[j], wk[1][j], qb1);
            qb2 = dot2acc(Pb.h[j], wk[2][j], qb2);
        }

        // 8-lane reductions (3 DPP steps each).
        reduce8_3(qa0, qa1, qa2);
        reduce8_3(qb0, qb1, qb2);

        if (sl < 5) {
            if (cea < E)
                out[(size_t)cea * 5 + sl] = qa0 * s0 + qa1 * s1 + qa2 * s2 + bua + bva;
            if (ceb < E)
                out[(size_t)ceb * 5 + sl] = qb0 * s0 + qb1 * s1 + qb2 * s2 + bub + bvb;
        }
    }
}

// ---------- fallback: direct fp32 (only if ws too small; normally unused) ---
__device__ __forceinline__ void reduce16_3f(float& a, float& b, float& c) {
    a = dpp_add<0xB1>(a);  b = dpp_add<0xB1>(b);  c = dpp_add<0xB1>(c);
    a = dpp_add<0x4E>(a);  b = dpp_add<0x4E>(b);  c = dpp_add<0x4E>(c);
    a = dpp_add<0x124>(a); b = dpp_add<0x124>(b); c = dpp_add<0x124>(c);
    a = dpp_add<0x128>(a); b = dpp_add<0x128>(b); c = dpp_add<0x128>(c);
}

__global__ __launch_bounds__(256) void bilinear_edges_f32(
    const float* __restrict__ u_feat, const float* __restrict__ v_feat,
    const float* __restrict__ W, const float* __restrict__ scalars,
    const float* __restrict__ u_bias, const float* __restrict__ v_bias,
    const int* __restrict__ u_idx, const int* __restrict__ v_idx,
    float* __restrict__ out, int E)
{
    const int tid    = blockIdx.x * blockDim.x + threadIdx.x;
    const int sl     = threadIdx.x & 15;
    const int group  = tid >> 4;
    const int ngroup = (gridDim.x * blockDim.x) >> 4;

    const int d0 = sl * 4;
    float w0[4], w1[4], w2[4];
    #pragma unroll
    for (int t = 0; t < 4; ++t) {
        w0[t] = W[0 * 64 + d0 + t];
        w1[t] = W[1 * 64 + d0 + t];
        w2[t] = W[2 * 64 + d0 + t];
    }
    float s0 = 0.f, s1 = 0.f, s2 = 0.f;
    if (sl < 5) { s0 = scalars[sl]; s1 = scalars[5 + sl]; s2 = scalars[10 + sl]; }

    for (int e = group; e < E; e += ngroup) {
        const int uu = u_idx[e];
        const int vv = v_idx[e];
        const float4 u4 = *reinterpret_cast<const float4*>(u_feat + (size_t)uu * 64 + d0);
        const float4 v4 = *reinterpret_cast<const float4*>(v_feat + (size_t)vv * 64 + d0);
        float ubx = 0.f, vbx = 0.f;
        if (sl < 5) { ubx = u_bias[(size_t)uu * 5 + sl]; vbx = v_bias[(size_t)vv * 5 + sl]; }

        const float p0 = u4.x * v4.x, p1 = u4.y * v4.y,
                    p2 = u4.z * v4.z, p3 = u4.w * v4.w;
        float q0 = p0*w0[0] + p1*w0[1] + p2*w0[2] + p3*w0[3];
        float q1 = p0*w1[0] + p1*w1[1] + p2*w1[2] + p3*w1[3];
        float q2 = p0*w2[0] + p1*w2[1] + p2*w2[2] + p3*w2[3];
        reduce16_3f(q0, q1, q2);
        if (sl < 5)
            out[(size_t)e * 5 + sl] = q0 * s0 + q1 * s1 + q2 * s2 + ubx + vbx;
    }
}

extern "C" void kernel_launch(void* const* d_in, const int* in_sizes, int n_in,
                              void* d_out, int out_size, void* d_ws, size_t ws_size,
                              hipStream_t stream) {
    const float* u_feat  = (const float*)d_in[0];
    const float* v_feat  = (const float*)d_in[1];
    const float* W       = (const float*)d_in[2];
    const float* scalars = (const float*)d_in[3];
    const float* u_bias  = (const float*)d_in[4];
    const float* v_bias  = (const float*)d_in[5];
    const int*   u_idx   = (const int*)d_in[6];
    const int*   v_idx   = (const int*)d_in[7];
    float*       out     = (float*)d_out;

    const int nu = in_sizes[0];          // NUM_USERS * 64
    const int nv = in_sizes[1];          // NUM_ITEMS * 64
    const int E  = in_sizes[6];          // 2,000,000 edges

    const size_t ws_need = (size_t)(nu + nv) * sizeof(__half);

    if (ws_size >= ws_need) {
        __half* u_h = (__half*)d_ws;
        __half* v_h = u_h + nu;
        convert_tables_fp16<<<2048, 256, 0, stream>>>(u_feat, v_feat, u_h, v_h, nu, nv);
        bilinear_dot8<<<2048, 256, 0, stream>>>(
            u_h, v_h, W, scalars, u_bias, v_bias, u_idx, v_idx, out, E);
    } else {
        bilinear_edges_f32<<<2048, 256, 0, stream>>>(
            u_feat, v_feat, W, scalars, u_bias, v_bias, u_idx, v_idx, out, E);
    }
}

// Round 13
// 203.881 us; speedup vs baseline: 1.1050x; 1.1050x over previous
//
#include <hip/hip_runtime.h>
#include <hip/hip_fp16.h>

// BilinearMixture — FINAL (restore of R9, the proven 101us optimum).
// Factorial record across R2-R12: bytes/row (R5), L2-miss locality (R6),
// instruction count (R9), MLP (R9), lookup count (R11), L1 bypass (R12)
// each varied ~2x; time pinned at ~101-107us for all non-regressing
// variants. Regressions: MFMA low-MLP (R7, 172us), packed-row (R11, 123us),
// nontemporal loads (R12, 125us — L1 hits from ~20x/40x row reuse are
// load-bearing). Conclusion: random-gather service-rate floor (~31
// CU-cycles/edge); no counter saturates because the limiter is in-flight
// miss-queue occupancy. This kernel: fp16 tables in d_ws, 8 lanes/edge
// (16B f16x8 load = full row line per 8-lane group), v_pk_mul_f16 products,
// K=3 dot2 chains (f32 acc), 3-step DPP reduce, 2-round (16-edge) ILP.

typedef _Float16 f16x8 __attribute__((ext_vector_type(8)));
typedef _Float16 h2    __attribute__((ext_vector_type(2)));

union F16x8 { f16x8 v; h2 h[4]; };

template <int CTRL>
__device__ __forceinline__ float dpp_add(float x) {
    int t = __builtin_amdgcn_update_dpp(0, __float_as_int(x), CTRL, 0xF, 0xF, true);
    return x + __int_as_float(t);
}
// Sum (a,b,c) across each 8-lane group: xor1 (quad_perm 0xB1), xor2 (0x4E),
// then ROW_HALF_MIRROR (0x141) folds the two quads of each half-row.
__device__ __forceinline__ void reduce8_3(float& a, float& b, float& c) {
    a = dpp_add<0xB1>(a);  b = dpp_add<0xB1>(b);  c = dpp_add<0xB1>(c);
    a = dpp_add<0x4E>(a);  b = dpp_add<0x4E>(b);  c = dpp_add<0x4E>(c);
    a = dpp_add<0x141>(a); b = dpp_add<0x141>(b); c = dpp_add<0x141>(c);
}

__device__ __forceinline__ float dot2acc(h2 a, h2 b, float c) {
#if __has_builtin(__builtin_amdgcn_fdot2)
    return __builtin_amdgcn_fdot2(a, b, c, false);
#else
    return c + (float)a[0] * (float)b[0] + (float)a[1] * (float)b[1];
#endif
}

// ---------- conversion: fp32 tables -> fp16 in workspace (proven ~free) ----
__global__ __launch_bounds__(256) void convert_tables_fp16(
    const float* __restrict__ u_feat, const float* __restrict__ v_feat,
    __half* __restrict__ u_h, __half* __restrict__ v_h, int nu, int nv)
{
    const int tid  = blockIdx.x * blockDim.x + threadIdx.x;
    const int nthr = gridDim.x * blockDim.x;
    for (int i = tid * 4; i < nu; i += nthr * 4) {
        const float4 x = *reinterpret_cast<const float4*>(u_feat + i);
        *reinterpret_cast<__half2*>(u_h + i)     = __floats2half2_rn(x.x, x.y);
        *reinterpret_cast<__half2*>(u_h + i + 2) = __floats2half2_rn(x.z, x.w);
    }
    for (int i = tid * 4; i < nv; i += nthr * 4) {
        const float4 x = *reinterpret_cast<const float4*>(v_feat + i);
        *reinterpret_cast<__half2*>(v_h + i)     = __floats2half2_rn(x.x, x.y);
        *reinterpret_cast<__half2*>(v_h + i + 2) = __floats2half2_rn(x.z, x.w);
    }
}

// ---------- main: 8 lanes/edge, 2 rounds (16 edges) per wave-iteration -----
__global__ __launch_bounds__(256) void bilinear_dot8(
    const __half* __restrict__ u_h, const __half* __restrict__ v_h,
    const float* __restrict__ W, const float* __restrict__ scalars,
    const float* __restrict__ u_bias, const float* __restrict__ v_bias,
    const int* __restrict__ u_idx, const int* __restrict__ v_idx,
    float* __restrict__ out, int E)
{
    const int lane = threadIdx.x & 63;
    const int sl   = lane & 7;                      // lane in 8-group
    const int sg   = lane >> 3;                     // subgroup (edge slot) 0..7
    const int wid  = (blockIdx.x * blockDim.x + threadIdx.x) >> 6;
    const int nw   = (gridDim.x * blockDim.x) >> 6;

    // Lane's W slice, packed fp16: wk[k][j2] covers d = sl*8 + 2*j2 (+1).
    const int d0 = sl * 8;
    h2 wk[3][4];
    #pragma unroll
    for (int k = 0; k < 3; ++k)
        #pragma unroll
        for (int j = 0; j < 4; ++j) {
            wk[k][j][0] = (_Float16)W[k * 64 + d0 + 2 * j];
            wk[k][j][1] = (_Float16)W[k * 64 + d0 + 2 * j + 1];
        }
    float s0 = 0.f, s1 = 0.f, s2 = 0.f;
    if (sl < 5) { s0 = scalars[sl]; s1 = scalars[5 + sl]; s2 = scalars[10 + sl]; }

    const int step = nw * 16;
    int base = wid * 16;
    if (base >= E) return;

    // Prologue indices for both rounds; loop prefetches the next iteration's.
    int ea = base + sg, eb = base + 8 + sg;
    int ua = u_idx[min(ea, E - 1)], va = v_idx[min(ea, E - 1)];
    int ub = u_idx[min(eb, E - 1)], vb = v_idx[min(eb, E - 1)];

    for (; base < E; base += step) {
        const int cea = base + sg, ceb = base + 8 + sg;
        const int cua = ua, cva = va, cub = ub, cvb = vb;

        // Row gathers: 16B/lane; each instruction touches 8 distinct lines.
        F16x8 Ua, Va, Ub, Vb;
        Ua.v = *reinterpret_cast<const f16x8*>(u_h + (size_t)cua * 64 + d0);
        Va.v = *reinterpret_cast<const f16x8*>(v_h + (size_t)cva * 64 + d0);
        Ub.v = *reinterpret_cast<const f16x8*>(u_h + (size_t)cub * 64 + d0);
        Vb.v = *reinterpret_cast<const f16x8*>(v_h + (size_t)cvb * 64 + d0);

        // Prefetch next iteration's indices (breaks idx->gather chain).
        const int nb = base + step;
        if (nb < E) {
            const int nea = nb + sg, neb = nb + 8 + sg;
            ua = u_idx[min(nea, E - 1)]; va = v_idx[min(nea, E - 1)];
            ub = u_idx[min(neb, E - 1)]; vb = v_idx[min(neb, E - 1)];
        }

        // Bias gathers early (writer lanes only); hide under dot/reduce.
        float bua = 0.f, bva = 0.f, bub = 0.f, bvb = 0.f;
        if (sl < 5) {
            bua = u_bias[(size_t)cua * 5 + sl];
            bva = v_bias[(size_t)cva * 5 + sl];
            bub = u_bias[(size_t)cub * 5 + sl];
            bvb = v_bias[(size_t)cvb * 5 + sl];
        }

        // Products in fp16 (v_pk_mul_f16 x4 per round).
        F16x8 Pa, Pb;
        Pa.v = Ua.v * Va.v;
        Pb.v = Ub.v * Vb.v;

        // K=3 partials via dot2 chains (f32 accumulate, no cvt storm).
        float qa0 = 0.f, qa1 = 0.f, qa2 = 0.f;
        float qb0 = 0.f, qb1 = 0.f, qb2 = 0.f;
        #pragma unroll
        for (int j = 0; j < 4; ++j) {
            qa0 = dot2acc(Pa.h[j], wk[0][j], qa0);
            qa1 = dot2acc(Pa.h[j], wk[1][j], qa1);
            qa2 = dot2acc(Pa.h[j], wk[2][j], qa2);
            qb0 = dot2acc(Pb.h[j], wk[0][j], qb0);
            qb1 = dot2acc(Pb.h[j], wk[1][j], qb1);
            qb2 = dot2acc(Pb.h[j], wk[2][j], qb2);
        }

        // 8-lane reductions (3 DPP steps each).
        reduce8_3(qa0, qa1, qa2);
        reduce8_3(qb0, qb1, qb2);

        if (sl < 5) {
            if (cea < E)
                out[(size_t)cea * 5 + sl] = qa0 * s0 + qa1 * s1 + qa2 * s2 + bua + bva;
            if (ceb < E)
                out[(size_t)ceb * 5 + sl] = qb0 * s0 + qb1 * s1 + qb2 * s2 + bub + bvb;
        }
    }
}

// ---------- fallback: direct fp32 (only if ws too small; normally unused) ---
__device__ __forceinline__ void reduce16_3f(float& a, float& b, float& c) {
    a = dpp_add<0xB1>(a);  b = dpp_add<0xB1>(b);  c = dpp_add<0xB1>(c);
    a = dpp_add<0x4E>(a);  b = dpp_add<0x4E>(b);  c = dpp_add<0x4E>(c);
    a = dpp_add<0x124>(a); b = dpp_add<0x124>(b); c = dpp_add<0x124>(c);
    a = dpp_add<0x128>(a); b = dpp_add<0x128>(b); c = dpp_add<0x128>(c);
}

__global__ __launch_bounds__(256) void bilinear_edges_f32(
    const float* __restrict__ u_feat, const float* __restrict__ v_feat,
    const float* __restrict__ W, const float* __restrict__ scalars,
    const float* __restrict__ u_bias, const float* __restrict__ v_bias,
    const int* __restrict__ u_idx, const int* __restrict__ v_idx,
    float* __restrict__ out, int E)
{
    const int tid    = blockIdx.x * blockDim.x + threadIdx.x;
    const int sl     = threadIdx.x & 15;
    const int group  = tid >> 4;
    const int ngroup = (gridDim.x * blockDim.x) >> 4;

    const int d0 = sl * 4;
    float w0[4], w1[4], w2[4];
    #pragma unroll
    for (int t = 0; t < 4; ++t) {
        w0[t] = W[0 * 64 + d0 + t];
        w1[t] = W[1 * 64 + d0 + t];
        w2[t] = W[2 * 64 + d0 + t];
    }
    float s0 = 0.f, s1 = 0.f, s2 = 0.f;
    if (sl < 5) { s0 = scalars[sl]; s1 = scalars[5 + sl]; s2 = scalars[10 + sl]; }

    for (int e = group; e < E; e += ngroup) {
        const int uu = u_idx[e];
        const int vv = v_idx[e];
        const float4 u4 = *reinterpret_cast<const float4*>(u_feat + (size_t)uu * 64 + d0);
        const float4 v4 = *reinterpret_cast<const float4*>(v_feat + (size_t)vv * 64 + d0);
        float ubx = 0.f, vbx = 0.f;
        if (sl < 5) { ubx = u_bias[(size_t)uu * 5 + sl]; vbx = v_bias[(size_t)vv * 5 + sl]; }

        const float p0 = u4.x * v4.x, p1 = u4.y * v4.y,
                    p2 = u4.z * v4.z, p3 = u4.w * v4.w;
        float q0 = p0*w0[0] + p1*w0[1] + p2*w0[2] + p3*w0[3];
        float q1 = p0*w1[0] + p1*w1[1] + p2*w1[2] + p3*w1[3];
        float q2 = p0*w2[0] + p1*w2[1] + p2*w2[2] + p3*w2[3];
        reduce16_3f(q0, q1, q2);
        if (sl < 5)
            out[(size_t)e * 5 + sl] = q0 * s0 + q1 * s1 + q2 * s2 + ubx + vbx;
    }
}

extern "C" void kernel_launch(void* const* d_in, const int* in_sizes, int n_in,
                              void* d_out, int out_size, void* d_ws, size_t ws_size,
                              hipStream_t stream) {
    const float* u_feat  = (const float*)d_in[0];
    const float* v_feat  = (const float*)d_in[1];
    const float* W       = (const float*)d_in[2];
    const float* scalars = (const float*)d_in[3];
    const float* u_bias  = (const float*)d_in[4];
    const float* v_bias  = (const float*)d_in[5];
    const int*   u_idx   = (const int*)d_in[6];
    const int*   v_idx   = (const int*)d_in[7];
    float*       out     = (float*)d_out;

    const int nu = in_sizes[0];          // NUM_USERS * 64
    const int nv = in_sizes[1];          // NUM_ITEMS * 64
    const int E  = in_sizes[6];          // 2,000,000 edges

    const size_t ws_need = (size_t)(nu + nv) * sizeof(__half);

    if (ws_size >= ws_need) {
        __half* u_h = (__half*)d_ws;
        __half* v_h = u_h + nu;
        convert_tables_fp16<<<2048, 256, 0, stream>>>(u_feat, v_feat, u_h, v_h, nu, nv);
        bilinear_dot8<<<2048, 256, 0, stream>>>(
            u_h, v_h, W, scalars, u_bias, v_bias, u_idx, v_idx, out, E);
    } else {
        bilinear_edges_f32<<<2048, 256, 0, stream>>>(
            u_feat, v_feat, W, scalars, u_bias, v_bias, u_idx, v_idx, out, E);
    }
}